// Round 6
// baseline (188.552 us; speedup 1.0000x reference)
//
#include <hip/hip_runtime.h>
#include <cstdint>

// Fused single-head attention, B=4 S=2048 D=1024, fp32 in/out, bf16 MFMA compute.
// Pipeline: cast/pack -> QKV GEMM (v transposed) -> scores GEMM -> softmax -> PV GEMM.
// GEMM engine: m201-style 8-phase schedule. Tile BM x 256, 8 waves (2 x 4),
// BK=64. Per K-tile: 4 phases {ds_read changed sub-frags; stage unit(s) placed
// AFTER that unit's last reader this tile (WAR-safe); vmcnt counted once per
// tile (never 0 mid-loop); s_barrier; lgkmcnt(0)+sched_barrier; setprio(1);
// 16 MFMA; setprio(0); s_barrier}. Paired-row XOR swizzle in LDS (measured 0
// bank conflicts), staged via linear global_load_lds + inverse-swizzled source.
// R5 bug fixed: A0(t+2) was staged in P2 while A0's rows were still read in P3
// (dbuf (t+2)&1 == t&1) -> race. A0 now staged in P4 with A1; vmcnt unchanged.

typedef unsigned short u16;
typedef __attribute__((ext_vector_type(4))) float f32x4;
typedef __attribute__((ext_vector_type(8))) __bf16 bf16x8;

#define AS1(p) ((const __attribute__((address_space(1))) void*)(p))
#define AS3(p) ((__attribute__((address_space(3))) void*)(p))

#define SEQ 2048
#define DM 1024

template <int N> struct ic { static constexpr int v = N; };

// ---------- bf16 bit helpers ----------
__device__ __forceinline__ u16 f2b(float f) {
  uint32_t u = __builtin_bit_cast(uint32_t, f);
  u += 0x7FFFu + ((u >> 16) & 1u);   // RNE
  return (u16)(u >> 16);
}
__device__ __forceinline__ float b2f(uint32_t bits16) {
  return __builtin_bit_cast(float, bits16 << 16);
}

// ---------- converts ----------
__global__ __launch_bounds__(256) void cvt_x_kernel(const float* __restrict__ x,
                                                    u16* __restrict__ xb) {
  int i = (blockIdx.x * 256 + threadIdx.x) * 4;
  float4 v = *(const float4*)(x + i);
  ushort4 o;
  o.x = f2b(v.x); o.y = f2b(v.y); o.z = f2b(v.z); o.w = f2b(v.w);
  *(ushort4*)(xb + i) = o;
}

__global__ __launch_bounds__(256) void pack_w_kernel(const float* __restrict__ Wq,
                                                     const float* __restrict__ Wk,
                                                     const float* __restrict__ Wv,
                                                     u16* __restrict__ wcat) {
  int i = (blockIdx.x * 256 + threadIdx.x) * 4;   // over 3*2^20 elems
  const float* src;
  int j;
  if (i < (1 << 20))      { src = Wq; j = i; }
  else if (i < (2 << 20)) { src = Wk; j = i - (1 << 20); }
  else                    { src = Wv; j = i - (2 << 20); }
  float4 v = *(const float4*)(src + j);
  ushort4 o;
  o.x = f2b(v.x); o.y = f2b(v.y); o.z = f2b(v.z); o.w = f2b(v.w);
  *(ushort4*)(wcat + i) = o;
}

// ---------- 8-phase GEMM engine ----------
// C tile = BM x 256, BM = FM*32.  8 waves as 2 (wm) x 4 (wn); per-wave
// C = FM*16 x 64 = acc[FM][4] of 16x16 frags.  K-tile = 64 (2 kk halves).
// LDS per operand: 2 dbuf x (BM|256) rows x 64 cols bf16, swizzled
//   byte(row, c16B) = row*128 + ((c ^ (row&7))*16),  c = kk*4 + ch.
// Stage unit = 128 rows x 64 cols = 16 KB = 2 global_load_lds per thread.
//   A units/tile: FM==8 ? {A0,A1} : {A};  B units: {B0,B1} (col halves).
// Per tile t (unit's last reader in parens):
//   P1: read alo,blo(t); stage B1(t+1) [other dbuf];     Q(0,0)
//   P2: read bhi(t);                                     Q(0,1)
//   P3: read ahi(t);     stage B0(t+2) (bhi@P2 done);    Q(1,1)
//   P4: stage A0[,A1](t+2) (ahi@P3 done); vmcnt(W);      Q(1,0)
// W = 6 (FM=8) / 4 (FM=4) = exactly the loads issued at P3+P4 -> all of tile
// t+1 (incl. B1(t+1) from this P1) landed before P4's barrier. vmcnt always
// precedes its barrier so every wave's staged slice is covered (cross-wave).

#define BAR()  __builtin_amdgcn_s_barrier()
#define LGK0() do { asm volatile("s_waitcnt lgkmcnt(0)" ::: "memory"); \
                    __builtin_amdgcn_sched_barrier(0); } while (0)

template <int FM, int T>
__device__ __forceinline__ void gemm8p(const u16* __restrict__ A,
                                       const u16* __restrict__ Bt,
                                       int lda, int ldb, char* lds,
                                       f32x4 (&acc)[FM][4], int tid) {
  constexpr int MH  = FM / 2;
  constexpr int SZA = FM * 4096;          // bytes per A dbuf (BM rows * 128B)
  constexpr int VMS = (FM == 8) ? 6 : 4;  // steady-state vmcnt (loads)

  char* ldsA = lds;                        // 2 * SZA
  char* ldsB = lds + 2 * SZA;              // 2 * 32768

  const int l  = tid & 63, w = tid >> 6;
  const int wm = w >> 2, wn = w & 3;
  const int fr = l & 15, ch = l >> 4;
  const int laneq  = fr * 128 + ((ch ^ (fr & 7)) << 4);
  const int aslot0 = (FM == 8) ? wm * 16384 : wm * 8192;
  const int bslot0 = (wn >> 1) * 16384 + (wn & 1) * 8192;

  // staging geometry: linear LDS byte o = j*8192 + tid*16 in a 16KB unit
  const int srow  = tid >> 3;
  const int sclog = (tid & 7) ^ ((tid >> 3) & 7);
  const u16* gA = A + srow * lda + sclog * 8;
  const u16* gB = Bt + srow * ldb + sclog * 8;
  const int wlin = w * 1024;               // wave-uniform LDS base

  auto stageA = [&](int mh, int t) {
#pragma unroll
    for (int j = 0; j < 2; ++j)
      __builtin_amdgcn_global_load_lds(
          AS1(gA + (mh * 128 + j * 64) * lda + t * 64),
          AS3(ldsA + (t & 1) * SZA + ((FM == 8) ? mh * 16384 : 0) + j * 8192 + wlin),
          16, 0, 0);
  };
  auto stageB = [&](int bh, int t) {
#pragma unroll
    for (int j = 0; j < 2; ++j)
      __builtin_amdgcn_global_load_lds(
          AS1(gB + (bh * 128 + j * 64) * ldb + t * 64),
          AS3(ldsB + (t & 1) * 32768 + bh * 16384 + j * 8192 + wlin),
          16, 0, 0);
  };

  auto readA = [&](bf16x8 (&dst)[FM], int msub, int db) {
#pragma unroll
    for (int mf = 0; mf < MH; ++mf)
#pragma unroll
      for (int kk = 0; kk < 2; ++kk)
        dst[mf * 2 + kk] = *(const bf16x8*)(ldsA + db * SZA + aslot0 +
                                            msub * MH * 2048 + mf * 2048 +
                                            (laneq ^ (kk << 6)));
  };
  auto readB = [&](bf16x8 (&dst)[4], int nsub, int db) {
#pragma unroll
    for (int nf = 0; nf < 2; ++nf)
#pragma unroll
      for (int kk = 0; kk < 2; ++kk)
        dst[nf * 2 + kk] = *(const bf16x8*)(ldsB + db * 32768 + bslot0 +
                                            nsub * 4096 + nf * 2048 +
                                            (laneq ^ (kk << 6)));
  };

  auto mfmaQ = [&](int msub, int nsub, bf16x8 (&a)[FM], bf16x8 (&b)[4]) {
    __builtin_amdgcn_s_setprio(1);
#pragma unroll
    for (int mf = 0; mf < MH; ++mf)
#pragma unroll
      for (int nf = 0; nf < 2; ++nf)
#pragma unroll
        for (int kk = 0; kk < 2; ++kk)
          acc[msub * MH + mf][nsub * 2 + nf] =
              __builtin_amdgcn_mfma_f32_16x16x32_bf16(
                  a[mf * 2 + kk], b[nf * 2 + kk],
                  acc[msub * MH + mf][nsub * 2 + nf], 0, 0, 0);
    __builtin_amdgcn_s_setprio(0);
  };

  auto tile = [&](auto p1s, auto p234s, auto vmw, int t) {
    constexpr bool P1S  = (decltype(p1s)::v != 0);
    constexpr bool P23S = (decltype(p234s)::v != 0);
    constexpr int  VMW  = decltype(vmw)::v;
    const int db = t & 1;
    bf16x8 alo[FM], ahi[FM], blo[4], bhi[4];
    // P1
    readA(alo, 0, db); readB(blo, 0, db);
    if constexpr (P1S) stageB(1, t + 1);
    BAR(); LGK0();
    mfmaQ(0, 0, alo, blo);
    BAR();
    // P2
    readB(bhi, 1, db);
    BAR(); LGK0();
    mfmaQ(0, 1, alo, bhi);
    BAR();
    // P3
    readA(ahi, 1, db);
    if constexpr (P23S) stageB(0, t + 2);
    BAR(); LGK0();
    mfmaQ(1, 1, ahi, bhi);
    BAR();
    // P4  (A units staged here: their last reader ahi finished at P3)
    if constexpr (P23S) {
      stageA(0, t + 2);
      if constexpr (FM == 8) stageA(1, t + 2);
    }
    if constexpr (VMW >= 0)
      asm volatile("s_waitcnt vmcnt(%0)" :: "i"(VMW) : "memory");
    BAR(); LGK0();
    mfmaQ(1, 0, ahi, blo);
    BAR();
  };

  // prologue: stage tiles 0 and 1 fully, in per-tile unit order
#pragma unroll
  for (int tt = 0; tt < 2; ++tt) {
    if constexpr (FM == 8) { stageA(0, tt); stageB(0, tt); stageA(1, tt); stageB(1, tt); }
    else                   { stageA(0, tt); stageB(0, tt); stageB(1, tt); }
  }
#pragma unroll
  for (int m = 0; m < FM; ++m)
#pragma unroll
    for (int n = 0; n < 4; ++n)
#pragma unroll
      for (int j = 0; j < 4; ++j) acc[m][n][j] = 0.f;
  asm volatile("s_waitcnt vmcnt(%0)" :: "i"((FM == 8) ? 8 : 6) : "memory");
  BAR();

  tile(ic<0>{}, ic<1>{}, ic<VMS>{}, 0);        // B1(1) already staged in prologue
  for (int t = 1; t <= T - 3; ++t)
    tile(ic<1>{}, ic<1>{}, ic<VMS>{}, t);
  tile(ic<1>{}, ic<0>{}, ic<0>{}, T - 2);      // stages B1(T-1); drain
  tile(ic<0>{}, ic<0>{}, ic<-1>{}, T - 1);
}

// ---------- QKV GEMM: [8192 x 3072] = xb[8192x1024] * wcat[3072x1024]^T + bias ----------
// Tile 256x256; 1D grid 384 with XCD-bijective swizzle.
__global__ __launch_bounds__(512, 2) void qkv_gemm(const u16* __restrict__ xb,
                                                   const u16* __restrict__ wcat,
                                                   const float* __restrict__ bq,
                                                   const float* __restrict__ bk,
                                                   const float* __restrict__ bv,
                                                   u16* __restrict__ qb,
                                                   u16* __restrict__ kb,
                                                   u16* __restrict__ vtb) {
  __shared__ __align__(16) char lds[131072];
  const int tid = threadIdx.x;
  const int lin = blockIdx.x;               // 384 = 8 xcd * 48
  const int wgid = (lin & 7) * 48 + (lin >> 3);
  const int bx = wgid % 12, by = wgid / 12;
  const int bm = by * 256, bn = bx * 256;
  f32x4 acc[8][4];
  gemm8p<8, 16>(xb + bm * 1024, wcat + bn * 1024, 1024, 1024, lds, acc, tid);
  const int l = tid & 63, w = tid >> 6;
  const int wm = w >> 2, wn = w & 3;
  const int which = bn >> 10;               // uniform per block (256 | 1024)
  const float* bias = (which == 0) ? bq : (which == 1) ? bk : bv;
#pragma unroll
  for (int m = 0; m < 8; ++m)
#pragma unroll
    for (int n = 0; n < 4; ++n) {
      int col = bn + wn * 64 + n * 16 + (l & 15);
      int e = col & 1023;
      float bval = bias[e];
#pragma unroll
      for (int j = 0; j < 4; ++j) {
        int row = bm + wm * 128 + m * 16 + (l >> 4) * 4 + j;
        u16 hb = f2b(acc[m][n][j] + bval);
        if (which == 0)      qb[row * 1024 + e] = hb;
        else if (which == 1) kb[row * 1024 + e] = hb;
        else { int b = row >> 11, s = row & 2047; vtb[(b << 21) + e * 2048 + s] = hb; }
      }
    }
}

// ---------- scores GEMM per batch: sb = (q * k^T) / 32, bf16 ----------
__global__ __launch_bounds__(512, 2) void scores_gemm(const u16* __restrict__ qb,
                                                      const u16* __restrict__ kb,
                                                      u16* __restrict__ sb) {
  __shared__ __align__(16) char lds[131072];
  const int tid = threadIdx.x;
  const int lin = blockIdx.x;               // 256 = 8 xcd * 32
  const int wgid = (lin & 7) * 32 + (lin >> 3);
  const int b = wgid >> 6, r = wgid & 63;
  const int by = r >> 3, bx = r & 7;
  const int bm = by * 256, bn = bx * 256;
  f32x4 acc[8][4];
  gemm8p<8, 16>(qb + b * (SEQ * DM) + bm * 1024,
                kb + b * (SEQ * DM) + bn * 1024, 1024, 1024, lds, acc, tid);
  u16* out = sb + (size_t)b * SEQ * SEQ;
  const int l = tid & 63, w = tid >> 6;
  const int wm = w >> 2, wn = w & 3;
#pragma unroll
  for (int m = 0; m < 8; ++m)
#pragma unroll
    for (int n = 0; n < 4; ++n) {
      int col = bn + wn * 64 + n * 16 + (l & 15);
#pragma unroll
      for (int j = 0; j < 4; ++j) {
        int row = bm + wm * 128 + m * 16 + (l >> 4) * 4 + j;
        out[row * 2048 + col] = f2b(acc[m][n][j] * 0.03125f);
      }
    }
}

// ---------- row softmax: 2048-wide rows, bf16 in, bf16 out ----------
__global__ __launch_bounds__(256) void softmax_k(const u16* __restrict__ sb,
                                                 u16* __restrict__ pb) {
  __shared__ float red[8];
  int row = blockIdx.x;
  const u16* src = sb + (size_t)row * 2048;
  u16* dst = pb + (size_t)row * 2048;
  int t = threadIdx.x;
  uint4 raw = *(const uint4*)(src + t * 8);
  uint32_t rw[4] = {raw.x, raw.y, raw.z, raw.w};
  float v[8];
#pragma unroll
  for (int q = 0; q < 4; ++q) {
    v[2 * q]     = b2f(rw[q] & 0xFFFFu);
    v[2 * q + 1] = __builtin_bit_cast(float, rw[q] & 0xFFFF0000u);
  }
  float m = v[0];
#pragma unroll
  for (int j = 1; j < 8; ++j) m = fmaxf(m, v[j]);
  for (int off = 32; off; off >>= 1) m = fmaxf(m, __shfl_xor(m, off));
  int w = t >> 6, l = t & 63;
  if (l == 0) red[w] = m;
  __syncthreads();
  m = fmaxf(fmaxf(red[0], red[1]), fmaxf(red[2], red[3]));
  float e[8], s = 0.f;
#pragma unroll
  for (int j = 0; j < 8; ++j) { e[j] = __expf(v[j] - m); s += e[j]; }
  for (int off = 32; off; off >>= 1) s += __shfl_xor(s, off);
  if (l == 0) red[4 + w] = s;
  __syncthreads();
  s = (red[4] + red[5]) + (red[6] + red[7]);
  float inv = 1.0f / s;
  uint32_t o[4];
#pragma unroll
  for (int q = 0; q < 4; ++q) {
    uint32_t lo = f2b(e[2 * q] * inv);
    uint32_t hi = f2b(e[2 * q + 1] * inv);
    o[q] = lo | (hi << 16);
  }
  *(uint4*)(dst + t * 8) = make_uint4(o[0], o[1], o[2], o[3]);
}

// ---------- PV GEMM per batch: out = pb[2048x2048] * v[2048x1024], fp32 out ----------
// Tile 128x256 (FM=4); grid 256 blocks (full machine).
__global__ __launch_bounds__(512, 2) void pv_gemm(const u16* __restrict__ pb,
                                                  const u16* __restrict__ vtb,
                                                  float* __restrict__ out) {
  __shared__ __align__(16) char lds[98304];   // 2*16KB (A) + 2*32KB (B)
  const int tid = threadIdx.x;
  const int lin = blockIdx.x;               // 256 = 8 xcd * 32
  const int wgid = (lin & 7) * 32 + (lin >> 3);
  const int b = wgid >> 6, r = wgid & 63;   // 64 blocks/batch = 16 by x 4 bx
  const int by = r >> 2, bx = r & 3;
  const int bm = by * 128, bn = bx * 256;
  f32x4 acc[4][4];
  gemm8p<4, 32>(pb + (size_t)b * SEQ * SEQ + bm * 2048,
                vtb + (size_t)b * DM * SEQ + bn * 2048, 2048, 2048,
                lds, acc, tid);
  float* o = out + (size_t)b * SEQ * DM;
  const int l = tid & 63, w = tid >> 6;
  const int wm = w >> 2, wn = w & 3;
#pragma unroll
  for (int m = 0; m < 4; ++m)
#pragma unroll
    for (int n = 0; n < 4; ++n) {
      int col = bn + wn * 64 + n * 16 + (l & 15);
#pragma unroll
      for (int j = 0; j < 4; ++j) {
        int row = bm + wm * 64 + m * 16 + (l >> 4) * 4 + j;
        o[row * 1024 + col] = acc[m][n][j];
      }
    }
}

// ---------- launch ----------
extern "C" void kernel_launch(void* const* d_in, const int* in_sizes, int n_in,
                              void* d_out, int out_size, void* d_ws, size_t ws_size,
                              hipStream_t stream) {
  const float* x  = (const float*)d_in[0];
  const float* Wq = (const float*)d_in[1];
  const float* bq = (const float*)d_in[2];
  const float* Wk = (const float*)d_in[3];
  const float* bk = (const float*)d_in[4];
  const float* Wv = (const float*)d_in[5];
  const float* bv = (const float*)d_in[6];
  float* out = (float*)d_out;

  char* ws = (char*)d_ws;
  u16* xb   = (u16*)(ws);                 // 16 MB  bf16 x            [8192][1024]
  u16* wcat = (u16*)(ws + 16777216);      //  6 MB  bf16 Wq|Wk|Wv     [3072][1024]
  u16* qb   = (u16*)(ws + 23068672);      // 16 MB  bf16 q            [4][2048][1024]
  u16* kb   = (u16*)(ws + 39845888);      // 16 MB  bf16 k            [4][2048][1024]
  u16* vtb  = (u16*)(ws + 56623104);      // 16 MB  bf16 v^T          [4][1024][2048]
  u16* sb   = (u16*)(ws + 73400320);      // 32 MB  bf16 scores       [4][2048][2048]
  u16* pb   = (u16*)(ws + 106954752);     // 32 MB  bf16 probs        [4][2048][2048]

  cvt_x_kernel<<<8192, 256, 0, stream>>>(x, xb);
  pack_w_kernel<<<3072, 256, 0, stream>>>(Wq, Wk, Wv, wcat);
  qkv_gemm<<<384, 512, 0, stream>>>(xb, wcat, bq, bk, bv, qb, kb, vtb);
  scores_gemm<<<256, 512, 0, stream>>>(qb, kb, sb);
  softmax_k<<<8192, 256, 0, stream>>>(sb, pb);
  pv_gemm<<<256, 512, 0, stream>>>(pb, vtb, out);
}

// Round 7
// 188.523 us; speedup vs baseline: 1.0002x; 1.0002x over previous
//
#include <hip/hip_runtime.h>
#include <cstdint>

// Fused single-head attention, B=4 S=2048 D=1024, fp32 in/out, bf16 MFMA compute.
// Pipeline: cast/pack -> QKV GEMM (v transposed) -> scores GEMM -> softmax -> PV GEMM.
// GEMM engine: m201-style 8-phase schedule. Tile BM x 256, 8 waves (2 x 4),
// BK=64. Per K-tile: 4 phases {ds_read changed sub-frags; stage unit(s) placed
// AFTER that unit's last reader this tile (WAR-safe); vmcnt counted once per
// tile (never 0 mid-loop); s_barrier; lgkmcnt(0); setprio(1); 16 MFMA;
// setprio(0); s_barrier}. Paired-row XOR swizzle in LDS (measured 0 bank
// conflicts), staged via linear global_load_lds + inverse-swizzled source.
// R7 change (single variable vs R6): removed ALL sched_barrier(0) and all
// "memory" clobbers on waitcnt asm. R6's per-phase full scheduling fence
// matched m141's measured 874->510 TF order-pinning regression; our ds_reads
// are compiler-tracked C++ loads (rule 18 applies only to asm ds_read), so
// the compiler's own dep-waits + the bare lgkmcnt(0) (as in m201) suffice.

typedef unsigned short u16;
typedef __attribute__((ext_vector_type(4))) float f32x4;
typedef __attribute__((ext_vector_type(8))) __bf16 bf16x8;

#define AS1(p) ((const __attribute__((address_space(1))) void*)(p))
#define AS3(p) ((__attribute__((address_space(3))) void*)(p))

#define SEQ 2048
#define DM 1024

template <int N> struct ic { static constexpr int v = N; };

// ---------- bf16 bit helpers ----------
__device__ __forceinline__ u16 f2b(float f) {
  uint32_t u = __builtin_bit_cast(uint32_t, f);
  u += 0x7FFFu + ((u >> 16) & 1u);   // RNE
  return (u16)(u >> 16);
}
__device__ __forceinline__ float b2f(uint32_t bits16) {
  return __builtin_bit_cast(float, bits16 << 16);
}

// ---------- converts ----------
__global__ __launch_bounds__(256) void cvt_x_kernel(const float* __restrict__ x,
                                                    u16* __restrict__ xb) {
  int i = (blockIdx.x * 256 + threadIdx.x) * 4;
  float4 v = *(const float4*)(x + i);
  ushort4 o;
  o.x = f2b(v.x); o.y = f2b(v.y); o.z = f2b(v.z); o.w = f2b(v.w);
  *(ushort4*)(xb + i) = o;
}

__global__ __launch_bounds__(256) void pack_w_kernel(const float* __restrict__ Wq,
                                                     const float* __restrict__ Wk,
                                                     const float* __restrict__ Wv,
                                                     u16* __restrict__ wcat) {
  int i = (blockIdx.x * 256 + threadIdx.x) * 4;   // over 3*2^20 elems
  const float* src;
  int j;
  if (i < (1 << 20))      { src = Wq; j = i; }
  else if (i < (2 << 20)) { src = Wk; j = i - (1 << 20); }
  else                    { src = Wv; j = i - (2 << 20); }
  float4 v = *(const float4*)(src + j);
  ushort4 o;
  o.x = f2b(v.x); o.y = f2b(v.y); o.z = f2b(v.z); o.w = f2b(v.w);
  *(ushort4*)(wcat + i) = o;
}

// ---------- 8-phase GEMM engine ----------
// C tile = BM x 256, BM = FM*32.  8 waves as 2 (wm) x 4 (wn); per-wave
// C = FM*16 x 64 = acc[FM][4] of 16x16 frags.  K-tile = 64 (2 kk halves).
// LDS per operand: 2 dbuf x (BM|256) rows x 64 cols bf16, swizzled
//   byte(row, c16B) = row*128 + ((c ^ (row&7))*16),  c = kk*4 + ch.
// Stage unit = 128 rows x 64 cols = 16 KB = 2 global_load_lds per thread.
//   A units/tile: FM==8 ? {A0,A1} : {A};  B units: {B0,B1} (col halves).
// Per tile t (unit's last reader in parens):
//   P1: read alo,blo(t); stage B1(t+1) [other dbuf];     Q(0,0)
//   P2: read bhi(t);                                     Q(0,1)
//   P3: read ahi(t);     stage B0(t+2) (bhi@P2 done);    Q(1,1)
//   P4: stage A0[,A1](t+2) (ahi@P3 done); vmcnt(W);      Q(1,0)
// W = 6 (FM=8) / 4 (FM=4) = exactly the loads issued at P3+P4 -> all of tile
// t+1 (incl. B1(t+1) from this P1) landed before P4's barrier. vmcnt always
// precedes its barrier so every wave's staged slice is covered (cross-wave).

#define BAR()  __builtin_amdgcn_s_barrier()
#define LGK0() asm volatile("s_waitcnt lgkmcnt(0)")

template <int FM, int T>
__device__ __forceinline__ void gemm8p(const u16* __restrict__ A,
                                       const u16* __restrict__ Bt,
                                       int lda, int ldb, char* lds,
                                       f32x4 (&acc)[FM][4], int tid) {
  constexpr int MH  = FM / 2;
  constexpr int SZA = FM * 4096;          // bytes per A dbuf (BM rows * 128B)
  constexpr int VMS = (FM == 8) ? 6 : 4;  // steady-state vmcnt (loads)

  char* ldsA = lds;                        // 2 * SZA
  char* ldsB = lds + 2 * SZA;              // 2 * 32768

  const int l  = tid & 63, w = tid >> 6;
  const int wm = w >> 2, wn = w & 3;
  const int fr = l & 15, ch = l >> 4;
  const int laneq  = fr * 128 + ((ch ^ (fr & 7)) << 4);
  const int aslot0 = (FM == 8) ? wm * 16384 : wm * 8192;
  const int bslot0 = (wn >> 1) * 16384 + (wn & 1) * 8192;

  // staging geometry: linear LDS byte o = j*8192 + tid*16 in a 16KB unit
  const int srow  = tid >> 3;
  const int sclog = (tid & 7) ^ ((tid >> 3) & 7);
  const u16* gA = A + srow * lda + sclog * 8;
  const u16* gB = Bt + srow * ldb + sclog * 8;
  const int wlin = w * 1024;               // wave-uniform LDS base

  auto stageA = [&](int mh, int t) {
#pragma unroll
    for (int j = 0; j < 2; ++j)
      __builtin_amdgcn_global_load_lds(
          AS1(gA + (mh * 128 + j * 64) * lda + t * 64),
          AS3(ldsA + (t & 1) * SZA + ((FM == 8) ? mh * 16384 : 0) + j * 8192 + wlin),
          16, 0, 0);
  };
  auto stageB = [&](int bh, int t) {
#pragma unroll
    for (int j = 0; j < 2; ++j)
      __builtin_amdgcn_global_load_lds(
          AS1(gB + (bh * 128 + j * 64) * ldb + t * 64),
          AS3(ldsB + (t & 1) * 32768 + bh * 16384 + j * 8192 + wlin),
          16, 0, 0);
  };

  auto readA = [&](bf16x8 (&dst)[FM], int msub, int db) {
#pragma unroll
    for (int mf = 0; mf < MH; ++mf)
#pragma unroll
      for (int kk = 0; kk < 2; ++kk)
        dst[mf * 2 + kk] = *(const bf16x8*)(ldsA + db * SZA + aslot0 +
                                            msub * MH * 2048 + mf * 2048 +
                                            (laneq ^ (kk << 6)));
  };
  auto readB = [&](bf16x8 (&dst)[4], int nsub, int db) {
#pragma unroll
    for (int nf = 0; nf < 2; ++nf)
#pragma unroll
      for (int kk = 0; kk < 2; ++kk)
        dst[nf * 2 + kk] = *(const bf16x8*)(ldsB + db * 32768 + bslot0 +
                                            nsub * 4096 + nf * 2048 +
                                            (laneq ^ (kk << 6)));
  };

  auto mfmaQ = [&](int msub, int nsub, bf16x8 (&a)[FM], bf16x8 (&b)[4]) {
    __builtin_amdgcn_s_setprio(1);
#pragma unroll
    for (int mf = 0; mf < MH; ++mf)
#pragma unroll
      for (int nf = 0; nf < 2; ++nf)
#pragma unroll
        for (int kk = 0; kk < 2; ++kk)
          acc[msub * MH + mf][nsub * 2 + nf] =
              __builtin_amdgcn_mfma_f32_16x16x32_bf16(
                  a[mf * 2 + kk], b[nf * 2 + kk],
                  acc[msub * MH + mf][nsub * 2 + nf], 0, 0, 0);
    __builtin_amdgcn_s_setprio(0);
  };

  auto tile = [&](auto p1s, auto p234s, auto vmw, int t) {
    constexpr bool P1S  = (decltype(p1s)::v != 0);
    constexpr bool P23S = (decltype(p234s)::v != 0);
    constexpr int  VMW  = decltype(vmw)::v;
    const int db = t & 1;
    bf16x8 alo[FM], ahi[FM], blo[4], bhi[4];
    // P1
    readA(alo, 0, db); readB(blo, 0, db);
    if constexpr (P1S) stageB(1, t + 1);
    BAR(); LGK0();
    mfmaQ(0, 0, alo, blo);
    BAR();
    // P2
    readB(bhi, 1, db);
    BAR(); LGK0();
    mfmaQ(0, 1, alo, bhi);
    BAR();
    // P3
    readA(ahi, 1, db);
    if constexpr (P23S) stageB(0, t + 2);
    BAR(); LGK0();
    mfmaQ(1, 1, ahi, bhi);
    BAR();
    // P4  (A units staged here: their last reader ahi finished at P3)
    if constexpr (P23S) {
      stageA(0, t + 2);
      if constexpr (FM == 8) stageA(1, t + 2);
    }
    if constexpr (VMW >= 0)
      asm volatile("s_waitcnt vmcnt(%0)" :: "i"(VMW));
    BAR(); LGK0();
    mfmaQ(1, 0, ahi, blo);
    BAR();
  };

  // prologue: stage tiles 0 and 1 fully, in per-tile unit order
#pragma unroll
  for (int tt = 0; tt < 2; ++tt) {
    if constexpr (FM == 8) { stageA(0, tt); stageB(0, tt); stageA(1, tt); stageB(1, tt); }
    else                   { stageA(0, tt); stageB(0, tt); stageB(1, tt); }
  }
#pragma unroll
  for (int m = 0; m < FM; ++m)
#pragma unroll
    for (int n = 0; n < 4; ++n)
#pragma unroll
      for (int j = 0; j < 4; ++j) acc[m][n][j] = 0.f;
  asm volatile("s_waitcnt vmcnt(%0)" :: "i"((FM == 8) ? 8 : 6));
  BAR();

  tile(ic<0>{}, ic<1>{}, ic<VMS>{}, 0);        // B1(1) already staged in prologue
  for (int t = 1; t <= T - 3; ++t)
    tile(ic<1>{}, ic<1>{}, ic<VMS>{}, t);
  tile(ic<1>{}, ic<0>{}, ic<0>{}, T - 2);      // stages B1(T-1); drain
  tile(ic<0>{}, ic<0>{}, ic<-1>{}, T - 1);
}

// ---------- QKV GEMM: [8192 x 3072] = xb[8192x1024] * wcat[3072x1024]^T + bias ----------
// Tile 256x256; 1D grid 384 with XCD-bijective swizzle.
__global__ __launch_bounds__(512, 2) void qkv_gemm(const u16* __restrict__ xb,
                                                   const u16* __restrict__ wcat,
                                                   const float* __restrict__ bq,
                                                   const float* __restrict__ bk,
                                                   const float* __restrict__ bv,
                                                   u16* __restrict__ qb,
                                                   u16* __restrict__ kb,
                                                   u16* __restrict__ vtb) {
  __shared__ __align__(16) char lds[131072];
  const int tid = threadIdx.x;
  const int lin = blockIdx.x;               // 384 = 8 xcd * 48
  const int wgid = (lin & 7) * 48 + (lin >> 3);
  const int bx = wgid % 12, by = wgid / 12;
  const int bm = by * 256, bn = bx * 256;
  f32x4 acc[8][4];
  gemm8p<8, 16>(xb + bm * 1024, wcat + bn * 1024, 1024, 1024, lds, acc, tid);
  const int l = tid & 63, w = tid >> 6;
  const int wm = w >> 2, wn = w & 3;
  const int which = bn >> 10;               // uniform per block (256 | 1024)
  const float* bias = (which == 0) ? bq : (which == 1) ? bk : bv;
#pragma unroll
  for (int m = 0; m < 8; ++m)
#pragma unroll
    for (int n = 0; n < 4; ++n) {
      int col = bn + wn * 64 + n * 16 + (l & 15);
      int e = col & 1023;
      float bval = bias[e];
#pragma unroll
      for (int j = 0; j < 4; ++j) {
        int row = bm + wm * 128 + m * 16 + (l >> 4) * 4 + j;
        u16 hb = f2b(acc[m][n][j] + bval);
        if (which == 0)      qb[row * 1024 + e] = hb;
        else if (which == 1) kb[row * 1024 + e] = hb;
        else { int b = row >> 11, s = row & 2047; vtb[(b << 21) + e * 2048 + s] = hb; }
      }
    }
}

// ---------- scores GEMM per batch: sb = (q * k^T) / 32, bf16 ----------
__global__ __launch_bounds__(512, 2) void scores_gemm(const u16* __restrict__ qb,
                                                      const u16* __restrict__ kb,
                                                      u16* __restrict__ sb) {
  __shared__ __align__(16) char lds[131072];
  const int tid = threadIdx.x;
  const int lin = blockIdx.x;               // 256 = 8 xcd * 32
  const int wgid = (lin & 7) * 32 + (lin >> 3);
  const int b = wgid >> 6, r = wgid & 63;
  const int by = r >> 3, bx = r & 7;
  const int bm = by * 256, bn = bx * 256;
  f32x4 acc[8][4];
  gemm8p<8, 16>(qb + b * (SEQ * DM) + bm * 1024,
                kb + b * (SEQ * DM) + bn * 1024, 1024, 1024, lds, acc, tid);
  u16* out = sb + (size_t)b * SEQ * SEQ;
  const int l = tid & 63, w = tid >> 6;
  const int wm = w >> 2, wn = w & 3;
#pragma unroll
  for (int m = 0; m < 8; ++m)
#pragma unroll
    for (int n = 0; n < 4; ++n) {
      int col = bn + wn * 64 + n * 16 + (l & 15);
#pragma unroll
      for (int j = 0; j < 4; ++j) {
        int row = bm + wm * 128 + m * 16 + (l >> 4) * 4 + j;
        out[row * 2048 + col] = f2b(acc[m][n][j] * 0.03125f);
      }
    }
}

// ---------- row softmax: 2048-wide rows, bf16 in, bf16 out ----------
__global__ __launch_bounds__(256) void softmax_k(const u16* __restrict__ sb,
                                                 u16* __restrict__ pb) {
  __shared__ float red[8];
  int row = blockIdx.x;
  const u16* src = sb + (size_t)row * 2048;
  u16* dst = pb + (size_t)row * 2048;
  int t = threadIdx.x;
  uint4 raw = *(const uint4*)(src + t * 8);
  uint32_t rw[4] = {raw.x, raw.y, raw.z, raw.w};
  float v[8];
#pragma unroll
  for (int q = 0; q < 4; ++q) {
    v[2 * q]     = b2f(rw[q] & 0xFFFFu);
    v[2 * q + 1] = __builtin_bit_cast(float, rw[q] & 0xFFFF0000u);
  }
  float m = v[0];
#pragma unroll
  for (int j = 1; j < 8; ++j) m = fmaxf(m, v[j]);
  for (int off = 32; off; off >>= 1) m = fmaxf(m, __shfl_xor(m, off));
  int w = t >> 6, l = t & 63;
  if (l == 0) red[w] = m;
  __syncthreads();
  m = fmaxf(fmaxf(red[0], red[1]), fmaxf(red[2], red[3]));
  float e[8], s = 0.f;
#pragma unroll
  for (int j = 0; j < 8; ++j) { e[j] = __expf(v[j] - m); s += e[j]; }
  for (int off = 32; off; off >>= 1) s += __shfl_xor(s, off);
  if (l == 0) red[4 + w] = s;
  __syncthreads();
  s = (red[4] + red[5]) + (red[6] + red[7]);
  float inv = 1.0f / s;
  uint32_t o[4];
#pragma unroll
  for (int q = 0; q < 4; ++q) {
    uint32_t lo = f2b(e[2 * q] * inv);
    uint32_t hi = f2b(e[2 * q + 1] * inv);
    o[q] = lo | (hi << 16);
  }
  *(uint4*)(dst + t * 8) = make_uint4(o[0], o[1], o[2], o[3]);
}

// ---------- PV GEMM per batch: out = pb[2048x2048] * v[2048x1024], fp32 out ----------
// Tile 128x256 (FM=4); grid 256 blocks (full machine).
__global__ __launch_bounds__(512, 2) void pv_gemm(const u16* __restrict__ pb,
                                                  const u16* __restrict__ vtb,
                                                  float* __restrict__ out) {
  __shared__ __align__(16) char lds[98304];   // 2*16KB (A) + 2*32KB (B)
  const int tid = threadIdx.x;
  const int lin = blockIdx.x;               // 256 = 8 xcd * 32
  const int wgid = (lin & 7) * 32 + (lin >> 3);
  const int b = wgid >> 6, r = wgid & 63;   // 64 blocks/batch = 16 by x 4 bx
  const int by = r >> 2, bx = r & 3;
  const int bm = by * 128, bn = bx * 256;
  f32x4 acc[4][4];
  gemm8p<4, 32>(pb + (size_t)b * SEQ * SEQ + bm * 2048,
                vtb + (size_t)b * DM * SEQ + bn * 2048, 2048, 2048,
                lds, acc, tid);
  float* o = out + (size_t)b * SEQ * DM;
  const int l = tid & 63, w = tid >> 6;
  const int wm = w >> 2, wn = w & 3;
#pragma unroll
  for (int m = 0; m < 4; ++m)
#pragma unroll
    for (int n = 0; n < 4; ++n) {
      int col = bn + wn * 64 + n * 16 + (l & 15);
#pragma unroll
      for (int j = 0; j < 4; ++j) {
        int row = bm + wm * 64 + m * 16 + (l >> 4) * 4 + j;
        o[row * 1024 + col] = acc[m][n][j];
      }
    }
}

// ---------- launch ----------
extern "C" void kernel_launch(void* const* d_in, const int* in_sizes, int n_in,
                              void* d_out, int out_size, void* d_ws, size_t ws_size,
                              hipStream_t stream) {
  const float* x  = (const float*)d_in[0];
  const float* Wq = (const float*)d_in[1];
  const float* bq = (const float*)d_in[2];
  const float* Wk = (const float*)d_in[3];
  const float* bk = (const float*)d_in[4];
  const float* Wv = (const float*)d_in[5];
  const float* bv = (const float*)d_in[6];
  float* out = (float*)d_out;

  char* ws = (char*)d_ws;
  u16* xb   = (u16*)(ws);                 // 16 MB  bf16 x            [8192][1024]
  u16* wcat = (u16*)(ws + 16777216);      //  6 MB  bf16 Wq|Wk|Wv     [3072][1024]
  u16* qb   = (u16*)(ws + 23068672);      // 16 MB  bf16 q            [4][2048][1024]
  u16* kb   = (u16*)(ws + 39845888);      // 16 MB  bf16 k            [4][2048][1024]
  u16* vtb  = (u16*)(ws + 56623104);      // 16 MB  bf16 v^T          [4][1024][2048]
  u16* sb   = (u16*)(ws + 73400320);      // 32 MB  bf16 scores       [4][2048][2048]
  u16* pb   = (u16*)(ws + 106954752);     // 32 MB  bf16 probs        [4][2048][2048]

  cvt_x_kernel<<<8192, 256, 0, stream>>>(x, xb);
  pack_w_kernel<<<3072, 256, 0, stream>>>(Wq, Wk, Wv, wcat);
  qkv_gemm<<<384, 512, 0, stream>>>(xb, wcat, bq, bk, bv, qb, kb, vtb);
  scores_gemm<<<256, 512, 0, stream>>>(qb, kb, sb);
  softmax_k<<<8192, 256, 0, stream>>>(sb, pb);
  pv_gemm<<<256, 512, 0, stream>>>(pb, vtb, out);
}